// Round 3
// baseline (1101.757 us; speedup 1.0000x reference)
//
#include <hip/hip_runtime.h>
#include <cfloat>
#include <cmath>

#define N_TOK 65536
#define N_E   2048
#define E_DIM 256
#define BETA  0.25

#define TM 64     // tokens per block
#define TN 64     // codes per tile
#define KC 16     // k-chunk staged for E

// ws layout (bytes)
#define WS_LOSSPART 0          // double[2048]  -> 16384
#define WS_A        16384      // float[65536]  -> 278528
#define WS_B        278528     // float[2048]   -> 286720
#define WS_IDXF     286720     // int[65536]    -> 548864
#define WS_COUNTS   548864     // int[2048]     -> 557056

// ---------------------------------------------------------------------------
// numpy f32 pairwise sum of squares of a 256-row, AVX512_SKX model:
// n=256 -> pairwise(128) + pairwise(128); each 128-block: 8 vector accs of
// width 16 (exactly the 128 elems), combined ((r0+r1)+(r2+r3))+((r4+r5)+(r6+r7))
// lane-wise, then GCC _mm512_reduce_add_ps halving tree.
// All ops via __f*_rn to forbid contraction/reassociation.
// ---------------------------------------------------------------------------
__device__ __forceinline__ float np_sq_pairwise256(const float* __restrict__ x) {
  float blk[2];
#pragma unroll
  for (int h = 0; h < 2; ++h) {
    const float* p = x + h * 128;
    float lane[16];
#pragma unroll
    for (int l = 0; l < 16; ++l) {
      const float q0 = __fmul_rn(p[l +   0], p[l +   0]);
      const float q1 = __fmul_rn(p[l +  16], p[l +  16]);
      const float q2 = __fmul_rn(p[l +  32], p[l +  32]);
      const float q3 = __fmul_rn(p[l +  48], p[l +  48]);
      const float q4 = __fmul_rn(p[l +  64], p[l +  64]);
      const float q5 = __fmul_rn(p[l +  80], p[l +  80]);
      const float q6 = __fmul_rn(p[l +  96], p[l +  96]);
      const float q7 = __fmul_rn(p[l + 112], p[l + 112]);
      lane[l] = __fadd_rn(__fadd_rn(__fadd_rn(q0, q1), __fadd_rn(q2, q3)),
                          __fadd_rn(__fadd_rn(q4, q5), __fadd_rn(q6, q7)));
    }
    float u[8];
#pragma unroll
    for (int l = 0; l < 8; ++l) u[l] = __fadd_rn(lane[l], lane[l + 8]);
    float v[4];
#pragma unroll
    for (int l = 0; l < 4; ++l) v[l] = __fadd_rn(u[l], u[l + 4]);
    const float w0 = __fadd_rn(v[0], v[2]);
    const float w1 = __fadd_rn(v[1], v[3]);
    blk[h] = __fadd_rn(w0, w1);
  }
  return __fadd_rn(blk[0], blk[1]);
}

__global__ __launch_bounds__(256) void k_ab(const float* __restrict__ z,
                                            const float* __restrict__ E,
                                            float* __restrict__ a,
                                            float* __restrict__ b) {
  const int r = blockIdx.x * 256 + threadIdx.x;
  if (r < N_TOK) {
    a[r] = np_sq_pairwise256(z + (size_t)r * E_DIM);
  } else {
    const int e = r - N_TOK;
    if (e < N_E) b[e] = np_sq_pairwise256(E + (size_t)e * E_DIM);
  }
}

__global__ void k_zero(int* __restrict__ counts) {
  const int i = blockIdx.x * 256 + threadIdx.x;
  if (i < N_E) counts[i] = 0;
}

// ---------------------------------------------------------------------------
// main pass. Per (t,j): m = sequential fused-FMA chain over k=0..255 (OpenBLAS
// sgemm micro-kernel model), D = fl(fl(a_t + b_j) - 2*m)  (numpy elementwise),
// argmin with first-occurrence tie-break via lexicographic (D, idx).
// ---------------------------------------------------------------------------
__global__ __launch_bounds__(256, 2) void k_main(
    const float* __restrict__ z, const float* __restrict__ E,
    const float* __restrict__ a, const float* __restrict__ b,
    int* __restrict__ idxF, float* __restrict__ out_idx) {
  extern __shared__ float sm[];
  float* zs = sm;               // [E_DIM][TM]  z-tile, transposed (k-major)
  float* es = sm + E_DIM * TM;  // [KC][TN]     E chunk, transposed (k-major)

  const int tid = threadIdx.x;
  const int tx = tid & 15;   // code group (4 codes per tile)
  const int ty = tid >> 4;   // token group (4 tokens)
  const size_t tok0 = (size_t)blockIdx.x * TM;

  // stage z transposed: zs[k][t] (exact bit copies)
  {
    const int t = tid >> 2;
    const int kq = (tid & 3) * 4;
    const float* zp = z + (tok0 + t) * E_DIM;
    for (int rep = 0; rep < E_DIM; rep += 16) {
      const int k = rep + kq;
      const float4 v = *(const float4*)(zp + k);
      zs[(k + 0) * TM + t] = v.x;
      zs[(k + 1) * TM + t] = v.y;
      zs[(k + 2) * TM + t] = v.z;
      zs[(k + 3) * TM + t] = v.w;
    }
  }

  float av[4];
#pragma unroll
  for (int i = 0; i < 4; ++i) av[i] = a[tok0 + ty * 4 + i];

  float v1[4];
  int j1[4];
#pragma unroll
  for (int i = 0; i < 4; ++i) { v1[i] = FLT_MAX; j1[i] = 0; }

  const int cs = tid >> 2;            // staging code
  const int kqs = (tid & 3) * 4;      // staging k offset
  for (int ct = 0; ct < N_E / TN; ++ct) {
    float acc[4][4];
#pragma unroll
    for (int i = 0; i < 4; ++i)
#pragma unroll
      for (int j = 0; j < 4; ++j) acc[i][j] = 0.f;

    const float* ep = E + (size_t)(ct * TN + cs) * E_DIM + kqs;
    for (int kc = 0; kc < E_DIM; kc += KC) {
      __syncthreads();
      {
        const float4 v = *(const float4*)(ep + kc);
        es[(kqs + 0) * TN + cs] = v.x;
        es[(kqs + 1) * TN + cs] = v.y;
        es[(kqs + 2) * TN + cs] = v.z;
        es[(kqs + 3) * TN + cs] = v.w;
      }
      __syncthreads();
      // strict k-ascending single-accumulator fused-FMA chain per (i,j)
#pragma unroll
      for (int k = 0; k < KC; ++k) {
        const float4 za = *(const float4*)&zs[(kc + k) * TM + ty * 4];
        const float4 eb = *(const float4*)&es[k * TN + tx * 4];
        const float zav[4] = {za.x, za.y, za.z, za.w};
        const float ebv[4] = {eb.x, eb.y, eb.z, eb.w};
#pragma unroll
        for (int i = 0; i < 4; ++i)
#pragma unroll
          for (int j = 0; j < 4; ++j)
            acc[i][j] = __fmaf_rn(zav[i], ebv[j], acc[i][j]);
      }
    }
    // epilogue: D = fl(fl(a+b) - 2*m), lex top-1 (codes ascending)
    const float4 b4 = *(const float4*)&b[ct * TN + tx * 4];
    const float bv[4] = {b4.x, b4.y, b4.z, b4.w};
    const int cbase = ct * TN + tx * 4;
#pragma unroll
    for (int i = 0; i < 4; ++i)
#pragma unroll
      for (int j = 0; j < 4; ++j) {
        const float X = __fadd_rn(av[i], bv[j]);
        const float D = __fsub_rn(X, __fmul_rn(2.0f, acc[i][j]));
        const int c = cbase + j;
        if (D < v1[i] || (D == v1[i] && c < j1[i])) { v1[i] = D; j1[i] = c; }
      }
  }

  // lexicographic (value, index) butterfly min across the 16 tx lanes
#pragma unroll
  for (int m = 1; m < 16; m <<= 1) {
#pragma unroll
    for (int i = 0; i < 4; ++i) {
      const float ov = __shfl_xor(v1[i], m, 64);
      const int   oj = __shfl_xor(j1[i], m, 64);
      if (ov < v1[i] || (ov == v1[i] && oj < j1[i])) { v1[i] = ov; j1[i] = oj; }
    }
  }
  if (tx == 0) {
#pragma unroll
    for (int i = 0; i < 4; ++i) {
      const int t = (int)tok0 + ty * 4 + i;
      idxF[t] = j1[i];
      out_idx[t] = (float)j1[i];
    }
  }
}

// gather z_q, write z_q_st = fl(z + fl(zq - z)), accumulate f64 loss partials
__global__ __launch_bounds__(256) void k_gather(
    const float* __restrict__ z, const float* __restrict__ E,
    const int* __restrict__ idxF, float* __restrict__ out0,
    double* __restrict__ lossPart) {
  double ls = 0.0;
  const int NU = N_TOK * (E_DIM / 4);  // float4 units
  for (int u = blockIdx.x * 256 + threadIdx.x; u < NU; u += 2048 * 256) {
    const int tok = u >> 6;
    const int d4 = (u & 63) * 4;
    const int c = idxF[tok];
    const float4 zq = *(const float4*)&E[(size_t)c * E_DIM + d4];
    const float4 zv = *(const float4*)&z[(size_t)tok * E_DIM + d4];
    float4 o;
    o.x = __fadd_rn(zv.x, __fsub_rn(zq.x, zv.x));
    o.y = __fadd_rn(zv.y, __fsub_rn(zq.y, zv.y));
    o.z = __fadd_rn(zv.z, __fsub_rn(zq.z, zv.z));
    o.w = __fadd_rn(zv.w, __fsub_rn(zq.w, zv.w));
    *(float4*)&out0[(size_t)u * 4] = o;
    double dx;
    dx = (double)zq.x - (double)zv.x; ls += dx * dx;
    dx = (double)zq.y - (double)zv.y; ls += dx * dx;
    dx = (double)zq.z - (double)zv.z; ls += dx * dx;
    dx = (double)zq.w - (double)zv.w; ls += dx * dx;
  }
  __shared__ double red[256];
  red[threadIdx.x] = ls;
  __syncthreads();
  for (int s = 128; s; s >>= 1) {
    if (threadIdx.x < s) red[threadIdx.x] += red[threadIdx.x + s];
    __syncthreads();
  }
  if (threadIdx.x == 0) lossPart[blockIdx.x] = red[0];
}

__global__ __launch_bounds__(256) void k_hist(const int* __restrict__ idxF,
                                              int* __restrict__ counts) {
  const int t = blockIdx.x * 256 + threadIdx.x;
  atomicAdd(&counts[idxF[t]], 1);
}

__global__ __launch_bounds__(256) void k_final(
    const double* __restrict__ lossPart, const int* __restrict__ counts,
    float* __restrict__ outLoss, float* __restrict__ outPerp) {
  __shared__ double rs[256], rh[256];
  double s = 0.0, h = 0.0;
  for (int j = threadIdx.x; j < 2048; j += 256) s += lossPart[j];
  for (int j = threadIdx.x; j < N_E; j += 256) {
    const double p = (double)counts[j] * (1.0 / (double)N_TOK);
    h -= p * log(p + 1e-10);
  }
  rs[threadIdx.x] = s;
  rh[threadIdx.x] = h;
  __syncthreads();
  for (int m = 128; m; m >>= 1) {
    if (threadIdx.x < m) {
      rs[threadIdx.x] += rs[threadIdx.x + m];
      rh[threadIdx.x] += rh[threadIdx.x + m];
    }
    __syncthreads();
  }
  if (threadIdx.x == 0) {
    outLoss[0] = (float)((1.0 + BETA) * rs[0] / (double)((size_t)N_TOK * E_DIM));
    outPerp[0] = (float)exp(rh[0]);
  }
}

extern "C" void kernel_launch(void* const* d_in, const int* in_sizes, int n_in,
                              void* d_out, int out_size, void* d_ws, size_t ws_size,
                              hipStream_t stream) {
  const float* z = (const float*)d_in[0];
  const float* E = (const float*)d_in[1];

  float* out0 = (float*)d_out;                       // z_q_st [65536*256]
  float* outLoss = out0 + (size_t)N_TOK * E_DIM;     // scalar
  float* outPerp = outLoss + 1;                      // scalar
  float* outIdx = outPerp + 1;                       // idx as float [65536]

  char* ws = (char*)d_ws;
  double* lossPart = (double*)(ws + WS_LOSSPART);
  float* a = (float*)(ws + WS_A);
  float* b = (float*)(ws + WS_B);
  int* idxF = (int*)(ws + WS_IDXF);
  int* counts = (int*)(ws + WS_COUNTS);

  (void)hipFuncSetAttribute(reinterpret_cast<const void*>(k_main),
                            hipFuncAttributeMaxDynamicSharedMemorySize, 69632);

  hipLaunchKernelGGL(k_zero, dim3(8), dim3(256), 0, stream, counts);
  hipLaunchKernelGGL(k_ab, dim3((N_TOK + N_E) / 256), dim3(256), 0, stream,
                     z, E, a, b);
  hipLaunchKernelGGL(k_main, dim3(N_TOK / TM), dim3(256), 69632, stream,
                     z, E, a, b, idxF, outIdx);
  hipLaunchKernelGGL(k_gather, dim3(2048), dim3(256), 0, stream,
                     z, E, idxF, out0, lossPart);
  hipLaunchKernelGGL(k_hist, dim3(N_TOK / 256), dim3(256), 0, stream, idxF, counts);
  hipLaunchKernelGGL(k_final, dim3(1), dim3(256), 0, stream,
                     lossPart, counts, outLoss, outPerp);
}